// Round 14
// baseline (294.480 us; speedup 1.0000x reference)
//
#include <hip/hip_runtime.h>
#include <hip/hip_fp16.h>
#include <cstdint>
#include <cstddef>

// ---------------------------------------------------------------------------
// Optical-flow estimator head, MI355X bf16 MFMA implementation. Round 14:
// convs switched to v_mfma_f32_32x32x16_bf16 (convr32): +14.7% matrix-pipe
// rate vs 16x16x32 (2495 vs 2176 TF measured), half the MFMA instruction
// count, identical LDS traffic. Wave split 1m x 4n (wave = BM co x 64 px).
// A/B frag: row/col = lane&31, k = (lane>>5)*8+e; C/D: col=lane&31,
// row = (reg&3)+8*(reg>>2)+4*(lane>>5) (m74/m101-verified).
// Everything else byte-identical to round 13 (best: 282.6us).
//
// X layout: NHWC bf16, [pix = b*65536 + h*256 + w][C_stride]
// conv1 K-order permuted: X1 = [feats 0..163 | volume 164..244 | zero 245..255]
// 3x3 weights packed [dy][APLN rows = dx*BM+co, padded][CI].
// ---------------------------------------------------------------------------

using short8 = __attribute__((ext_vector_type(8))) short;
using f32x4  = __attribute__((ext_vector_type(4))) float;
using f32x16 = __attribute__((ext_vector_type(16))) float;
typedef unsigned short u16;

__device__ __forceinline__ u16 rne_bf16(float f) {
  unsigned u = __float_as_uint(f);
  u += 0x7FFFu + ((u >> 16) & 1u);   // round-to-nearest-even
  return (u16)(u >> 16);
}

__device__ __forceinline__ void mfma32(const short8& a, const short8& b, f32x16& c) {
  asm("v_mfma_f32_32x32x16_bf16 %0, %1, %2, %0" : "+v"(c) : "v"(a), "v"(b));
}

__device__ __forceinline__ unsigned pk_f16(float a, float b) {
  unsigned r;
  asm("v_cvt_pkrtz_f16_f32 %0, %1, %2" : "=v"(r) : "v"(a), "v"(b));
  return r;
}

__device__ __forceinline__ void dot2(float& acc, unsigned a, unsigned b) {
  asm("v_dot2_f32_f16 %0, %1, %2, %0" : "+v"(acc) : "v"(a), "v"(b));
}

// async global -> LDS, 16B per lane (wave-uniform LDS base, per-lane source)
__device__ __forceinline__ void gload16(const void* g, void* l) {
  __builtin_amdgcn_global_load_lds(
      (const __attribute__((address_space(1))) unsigned int*)g,
      (__attribute__((address_space(3))) unsigned int*)l, 16, 0, 0);
}

// uint2 (4xf16) -> packed 2x bf16 words
__device__ __forceinline__ uint2 quad_to_bf16(uint2 v) {
  __half2 lo = *(__half2*)&v.x, hi = *(__half2*)&v.y;
  uint2 u;
  u.x = (unsigned)rne_bf16(__half2float(lo.x)) | ((unsigned)rne_bf16(__half2float(lo.y)) << 16);
  u.y = (unsigned)rne_bf16(__half2float(hi.x)) | ((unsigned)rne_bf16(__half2float(hi.y)) << 16);
  return u;
}

// ---------------------------------------------------------------------------
// Weight prep
// ---------------------------------------------------------------------------
__global__ __launch_bounds__(256) void prep1_kernel(const float* __restrict__ w1,
                                                    u16* __restrict__ w1p) {
  int idx = blockIdx.x * 256 + threadIdx.x;     // < 192*256
  int co = idx >> 8, cip = idx & 255;
  float v = 0.f;
  if (co < 160 && cip < 245) {
    int ci = (cip < 164) ? (cip + 81) : (cip - 164);
    v = w1[co * 245 + ci];
  }
  w1p[idx] = rne_bf16(v);
}

// 3x3 weights -> [dy][APLN][CIP] bf16, row = dx*BM + co (padded rows/ci zero)
template<int CO, int CIr, int BM, int APLN, int CIP>
__global__ __launch_bounds__(256) void prep3s_kernel(const float* __restrict__ w,
                                                     u16* __restrict__ wp) {
  int idx = blockIdx.x * 256 + threadIdx.x;     // < 3*APLN*CIP
  int ci = idx % CIP; int rest = idx / CIP;
  int row = rest % APLN; int dyp = rest / APLN;
  int dx = row / BM, co = row % BM;
  float v = 0.f;
  if (dx < 3 && co < CO && ci < CIr)
    v = w[(co * CIr + ci) * 9 + dyp * 3 + dx];
  wp[idx] = rne_bf16(v);
}

// padded biases: bp = [b1(160)|b2(128)|b3 pad128|b4(96)|b5(64)|b6 pad32], zbuf zeroed
__global__ __launch_bounds__(256) void prep_bias_kernel(const float* __restrict__ b1,
    const float* __restrict__ b2, const float* __restrict__ b3,
    const float* __restrict__ b4, const float* __restrict__ b5,
    const float* __restrict__ b6,
    float* __restrict__ bp, u16* __restrict__ zbuf) {
  int i = blockIdx.x * 256 + threadIdx.x;       // grid 3 blocks
  if (i < 128) zbuf[i] = 0;
  float v = 0.f;
  if (i < 160) v = b1[i];
  else if (i < 288) v = b2[i - 160];
  else if (i < 416) { int c = i - 288; v = (c < 112) ? b3[c] : 0.f; }
  else if (i < 512) v = b4[i - 416];
  else if (i < 576) v = b5[i - 512];
  else if (i < 608) { int c = i - 576; v = (c < 4) ? b6[c] : 0.f; }
  else return;
  bp[i] = v;
}

// ---------------------------------------------------------------------------
// quadize: f0/f1 NCHW f32 -> f16 quad planes [b][12][hw][4ch]. Register-only.
// ---------------------------------------------------------------------------
__global__ __launch_bounds__(256) void quadize_kernel(const float* __restrict__ f0,
                                                      const float* __restrict__ f1,
                                                      u16* __restrict__ f0q,
                                                      u16* __restrict__ f1q) {
  const int bid = blockIdx.x;
  const int qh = bid >> 9;             // 0/1
  const int b = (bid >> 8) & 1;
  const int h = bid & 255;
  const int hw = (h << 8) + threadIdx.x;
  const float* s0 = f0 + (((size_t)(b * 48 + qh * 24)) << 16) + hw;
  const float* s1 = f1 + (((size_t)(b * 48 + qh * 24)) << 16) + hw;
  u16* d0 = f0q + (((size_t)((b * 12 + qh * 6) << 16)) + hw) * 4;
  u16* d1 = f1q + (((size_t)((b * 12 + qh * 6) << 16)) + hw) * 4;
#pragma unroll
  for (int q = 0; q < 6; ++q) {
    uint2 u;
    u.x = pk_f16(s0[((size_t)(4 * q)) << 16],     s0[((size_t)(4 * q + 1)) << 16]);
    u.y = pk_f16(s0[((size_t)(4 * q + 2)) << 16], s0[((size_t)(4 * q + 3)) << 16]);
    *(uint2*)(d0 + (size_t)q * 262144) = u;
    uint2 v;
    v.x = pk_f16(s1[((size_t)(4 * q)) << 16],     s1[((size_t)(4 * q + 1)) << 16]);
    v.y = pk_f16(s1[((size_t)(4 * q + 2)) << 16], s1[((size_t)(4 * q + 3)) << 16]);
    *(uint2*)(d1 + (size_t)q * 262144) = v;
  }
}

// ---------------------------------------------------------------------------
// concat68: lf/lfl -> X1 ch 96..163.
// ---------------------------------------------------------------------------
__global__ __launch_bounds__(256) void concat68_kernel(const float* __restrict__ lf,
                                                       const float* __restrict__ lfl,
                                                       u16* __restrict__ X1) {
  __shared__ float s[16][68];
  const int t = threadIdx.x;
  const size_t px0 = (size_t)blockIdx.x * 64;
  const int b = blockIdx.x >> 10;
  const int hw0 = (blockIdx.x & 1023) * 64;

#pragma unroll 1
  for (int cc = 0; cc < 5; ++cc) {
    __syncthreads();
    {
      int px = t & 63, cg = t >> 6;
#pragma unroll
      for (int r = 0; r < 4; ++r) {
        int cl = cg * 4 + r;
        int c = cc * 16 + cl;           // 0..79 (68 used)
        int hw = hw0 + px;
        float v = 0.f;
        if (c < 64)       v = lf[(((size_t)(b * 64 + c)) << 16) + hw];
        else if (c < 68)  v = lfl[(((size_t)(b * 4 + (c - 64))) << 16) + hw];
        s[cl][px] = v;
      }
    }
    __syncthreads();
    {
      int px = t >> 2, g = t & 3;
      int cbase = cc * 16 + g * 4;
      if (cbase < 68) {
        ushort4 u;
        u.x = rne_bf16(s[g * 4 + 0][px]);
        u.y = rne_bf16(s[g * 4 + 1][px]);
        u.z = rne_bf16(s[g * 4 + 2][px]);
        u.w = rne_bf16(s[g * 4 + 3][px]);
        *(ushort4*)(X1 + (px0 + px) * 256 + 96 + cbase) = u;
      }
    }
  }
}

// ---------------------------------------------------------------------------
// corr5 (round-7 design, unchanged): async-staged windowed correlation.
// ---------------------------------------------------------------------------
template<int NDY>
__device__ __forceinline__ void corr_acc(const uint2* __restrict__ wb,
                                         const unsigned* __restrict__ f0p,
                                         float* __restrict__ cv,
                                         int row, int col, int dy0) {
#pragma unroll
  for (int d = 0; d < NDY; ++d) {
    const int r = row + dy0 + d;
#pragma unroll
    for (int q = 0; q < 3; ++q) {
      const uint2* base = wb + (q * 10 + r) * 80 + (col + 4);
#pragma unroll
      for (int dx = 0; dx < 9; ++dx) {
        const uint2 v = base[dx];
        dot2(cv[d * 9 + dx], v.x, f0p[2 * q]);
        dot2(cv[d * 9 + dx], v.y, f0p[2 * q + 1]);
      }
    }
  }
}

__global__ __launch_bounds__(256, 4) void corr5_kernel(const u16* __restrict__ f0q,
                                                       const u16* __restrict__ f1q,
                                                       const u16* __restrict__ zbuf,
                                                       u16* __restrict__ X1) {
  __shared__ char wlds[2][20480];        // [3q][10r][80c] x 8B = 19.2KB + pad
  const int bid = blockIdx.x;
  const int swz = (bid & 7) * 128 + (bid >> 3);   // XCD-contiguous, bijective
  const int b = swz >> 9, rest = swz & 511;
  const int hp = rest >> 2, ct = rest & 3;
  const int h0 = hp << 1, w0 = ct << 6;
  const int tid = threadIdx.x, lane = tid & 63, wv = tid >> 6;
  const int half = wv >> 1, row = wv & 1, col = lane;
  const int pixhw = ((h0 + row) << 8) + (w0 + col);
  const size_t pix = ((size_t)b << 16) + pixhw;

  const u16* srcp[5];
  bool okf[5];
#pragma unroll
  for (int ru = 0; ru < 5; ++ru) {
    int u = ru * 256 + tid;
    int uq = u / 400;                    // 0..2 real, 3 = pad
    int rem = u - uq * 400;
    int r = rem / 40, cu = rem - r * 40;
    int hin = h0 + r - 4;
    int wpx = w0 - 8 + 2 * cu;           // even
    bool ok = (u < 1200) && ((unsigned)hin < 256u) && ((unsigned)wpx < 256u);
    okf[ru] = ok;
    srcp[ru] = ok ? (f1q + (((size_t)((b * 12 + uq) << 16) + (hin << 8) + wpx) << 2))
                  : zbuf;
  }

  float cv[45];
#pragma unroll
  for (int t = 0; t < 45; ++t) cv[t] = 0.f;

#pragma unroll
  for (int ru = 0; ru < 5; ++ru)
    gload16(srcp[ru], &wlds[0][ru * 4096 + wv * 1024]);

#pragma unroll 1
  for (int cc = 0; cc < 4; ++cc) {
    __syncthreads();
    if (cc < 3) {
#pragma unroll
      for (int ru = 0; ru < 5; ++ru) {
        const u16* s = okf[ru] ? (srcp[ru] + (size_t)(cc + 1) * 786432) : zbuf;
        gload16(s, &wlds[(cc + 1) & 1][ru * 4096 + wv * 1024]);
      }
    }
    const uint2* wb = (const uint2*)&wlds[cc & 1][0];

    const u16* f0base = f0q + (((size_t)((b * 12 + cc * 3) << 16) + pixhw) << 2);
    uint2 q0 = *(const uint2*)(f0base);
    uint2 q1 = *(const uint2*)(f0base + 262144);
    uint2 q2 = *(const uint2*)(f0base + 524288);
    unsigned f0p[6] = {q0.x, q0.y, q1.x, q1.y, q2.x, q2.y};

    {
      u16* dst0 = X1 + pix * 256 + cc * 12;
      *(uint2*)(dst0)     = quad_to_bf16(q0);
      *(uint2*)(dst0 + 4) = quad_to_bf16(q1);
      *(uint2*)(dst0 + 8) = quad_to_bf16(q2);
    }
    {
      u16* dst1 = X1 + pix * 256 + 48 + cc * 12;
#pragma unroll
      for (int q = 0; q < 3; ++q) {
        uint2 v = wb[(q * 10 + row + 4) * 80 + (col + 8)];
        *(uint2*)(dst1 + 4 * q) = quad_to_bf16(v);
      }
    }
    if (half == 0) corr_acc<4>(wb, f0p, cv, row, col, 0);
    else           corr_acc<5>(wb, f0p, cv, row, col, 4);
  }

  u16* dst = X1 + pix * 256;
  const float sc = 1.0f / 48.0f;
  if (half == 0) {
#pragma unroll
    for (int qq = 0; qq < 9; ++qq) {
      u16 e[4];
#pragma unroll
      for (int j = 0; j < 4; ++j) {
        float v = cv[qq * 4 + j] * sc;
        v = v > 0.f ? v : 0.1f * v;
        e[j] = rne_bf16(v);
      }
      uint2 u;
      u.x = (unsigned)e[0] | ((unsigned)e[1] << 16);
      u.y = (unsigned)e[2] | ((unsigned)e[3] << 16);
      *(uint2*)(dst + 164 + qq * 4) = u;
    }
  } else {
#pragma unroll
    for (int qq = 0; qq < 14; ++qq) {
      u16 e[4];
#pragma unroll
      for (int j = 0; j < 4; ++j) {
        int t = qq * 4 + j;
        float v = 0.f;
        if (t < 45) {
          v = cv[t] * sc;
          v = v > 0.f ? v : 0.1f * v;
        }
        e[j] = rne_bf16(v);
      }
      uint2 u;
      u.x = (unsigned)e[0] | ((unsigned)e[1] << 16);
      u.y = (unsigned)e[2] | ((unsigned)e[3] << 16);
      *(uint2*)(dst + 200 + qq * 4) = u;
    }
  }
}

// ---------------------------------------------------------------------------
// Full-row merged-tap implicit-GEMM conv, 32x32x16 MFMA (round 14).
// Block = (batch, row h) x 256 px. 4 waves 1m x 4n: wave = BM co x 64 px.
// Frag layout: A/B row(col)=lane&31, k=(lane>>5)*8+e (mirrors 16x16x32);
// C/D col=lane&31, row=(reg&3)+8*(reg>>2)+4*(lane>>5) (m74/m101-verified).
// Staging / swizzle / 2-barrier phase structure identical to round 13.
// ---------------------------------------------------------------------------
template<int CI, int BM, int APLN, int KS, int OSTRIDE, bool LRELU, bool OBF, int COF32>
__global__ __launch_bounds__(256, 2) void convr32_kernel(const u16* __restrict__ Xin,
    const u16* __restrict__ Wp, const float* __restrict__ bias,
    const u16* __restrict__ zbuf, u16* __restrict__ Xout,
    float* __restrict__ outF) {
  constexpr int NCH = CI / 32;
  constexpr int NDX = (KS == 3) ? 3 : 1;
  constexpr int HALO = (KS == 3) ? 2 : 0;
  constexpr int AROUNDS = APLN / 64;
  constexpr int BROUNDS = (KS == 3) ? 5 : 4;   // 320 / 256 px-slots
  constexpr int BPXMAX = 256 + 2 * HALO;       // valid slot count
  constexpr int MF32 = BM / 32;
  constexpr int AELEMS = AROUNDS * 2048;       // u16
  constexpr int NPH = NDX * NCH;
  __shared__ u16 lds[AELEMS + BROUNDS * 2048];

  const int tid = threadIdx.x;
  const int lane = tid & 63, wn = tid >> 6;    // 4 waves, each 64 px
  const int bid = blockIdx.x;
  const int swz = (bid & 7) * 64 + (bid >> 3); // 512 blocks, bijective
  const int bi = swz >> 8;
  const int h = swz & 255;
  const int l31 = lane & 31, kg = lane >> 5;   // k-group (8-elem half)

  size_t aofs[AROUNDS];
#pragma unroll
  for (int r = 0; r < AROUNDS; ++r) {
    int slot = r * 256 + tid;
    int row = slot >> 2, sp = slot & 3;
    int seg = sp ^ ((row >> 1) & 3);
    aofs[r] = (size_t)row * CI + seg * 8;
  }
  size_t bofs[BROUNDS];
  bool bcolv[BROUNDS];
#pragma unroll
  for (int r = 0; r < BROUNDS; ++r) {
    int slot = r * 256 + tid;
    int pxl = slot >> 2, sp = slot & 3;
    int seg = sp ^ ((pxl >> 1) & 3);
    int px = pxl - HALO;
    bcolv[r] = ((unsigned)px < 256u) && (pxl < BPXMAX);
    bofs[r] = (size_t)px * CI + seg * 8;
  }

  f32x16 acc[MF32][2];
#pragma unroll
  for (int m = 0; m < MF32; ++m)
#pragma unroll
    for (int n = 0; n < 2; ++n)
#pragma unroll
      for (int e = 0; e < 16; ++e) acc[m][n][e] = 0.f;

  int dy = 0, c = 0;
#pragma unroll 1
  for (int ph = 0; ph < NPH; ++ph) {
    __syncthreads();                 // protect LDS from prev phase readers
    const u16* Wph = Wp + ((size_t)dy * APLN) * CI + c * 32;
#pragma unroll
    for (int r = 0; r < AROUNDS; ++r)
      gload16(Wph + aofs[r], &lds[r * 2048 + wn * 512]);
    const int hin = (KS == 3) ? (h + dy - 1) : h;
    const bool rv = (unsigned)hin < 256u;
    const u16* Brow = Xin + ((size_t)((bi << 8) + (rv ? hin : 0)) << 8) * CI + c * 32;
#pragma unroll
    for (int r = 0; r < BROUNDS; ++r) {
      const u16* src = (rv && bcolv[r]) ? (Brow + bofs[r]) : zbuf;
      gload16(src, &lds[AELEMS + r * 2048 + wn * 512]);
    }
    __syncthreads();                 // staging complete

#pragma unroll
    for (int dx = 0; dx < NDX; ++dx) {
#pragma unroll
      for (int kh = 0; kh < 2; ++kh) {
        const int segk = kh * 2 + kg;
        short8 bfr[2];
#pragma unroll
        for (int n = 0; n < 2; ++n) {
          int p = wn * 64 + n * 32 + l31;
          int pxl = (KS == 3) ? (p + dx + 1) : p;   // slot = px + HALO
          int ba = (AELEMS * 2) + pxl * 64 + ((segk ^ ((pxl >> 1) & 3)) << 4);
          bfr[n] = *(const short8*)((const char*)lds + ba);
        }
        short8 afr[MF32];
#pragma unroll
        for (int m = 0; m < MF32; ++m) {
          int row = dx * BM + m * 32 + l31;
          int aa = row * 64 + ((segk ^ ((row >> 1) & 3)) << 4);
          afr[m] = *(const short8*)((const char*)lds + aa);
        }
#pragma unroll
        for (int m = 0; m < MF32; ++m)
#pragma unroll
          for (int n = 0; n < 2; ++n) mfma32(afr[m], bfr[n], acc[m][n]);
      }
    }
    if (++c == NCH) { c = 0; ++dy; }
  }
  asm volatile("s_nop 7\n\ts_nop 7");   // MFMA -> VALU hazard insurance

  const size_t pixbase = ((size_t)((bi << 8) + h)) << 8;
#pragma unroll
  for (int m = 0; m < MF32; ++m) {
#pragma unroll
    for (int n = 0; n < 2; ++n) {
      const int px = wn * 64 + n * 32 + l31;
      f32x16 v = acc[m][n];
#pragma unroll
      for (int q = 0; q < 4; ++q) {
        const int co = m * 32 + q * 8 + kg * 4;   // + (0..3) via reg&3
        float t[4];
#pragma unroll
        for (int r = 0; r < 4; ++r) {
          float x = v[q * 4 + r] + bias[co + r];
          if (LRELU) x = x > 0.f ? x : 0.1f * x;
          t[r] = x;
        }
        if (OBF) {
          ushort4 u;
          u.x = rne_bf16(t[0]); u.y = rne_bf16(t[1]);
          u.z = rne_bf16(t[2]); u.w = rne_bf16(t[3]);
          *(ushort4*)(Xout + (pixbase + px) * OSTRIDE + co) = u;
        }
        if (COF32 > 0) {
#pragma unroll
          for (int r = 0; r < 4; ++r) {
            int cch = co + r;
            if (cch < COF32)
              outF[(((size_t)bi * COF32 + cch) << 16) + (h << 8) + px] = t[r];
          }
        }
      }
    }
  }
}

// ---------------------------------------------------------------------------
extern "C" void kernel_launch(void* const* d_in, const int* in_sizes, int n_in,
                              void* d_out, int out_size, void* d_ws, size_t ws_size,
                              hipStream_t stream) {
  const float* feat0 = (const float*)d_in[0];
  const float* feat1 = (const float*)d_in[1];
  const float* lfeat = (const float*)d_in[2];
  const float* lflow = (const float*)d_in[3];
  const float* w1 = (const float*)d_in[4];  const float* b1 = (const float*)d_in[5];
  const float* w2 = (const float*)d_in[6];  const float* b2 = (const float*)d_in[7];
  const float* w3 = (const float*)d_in[8];  const float* b3 = (const float*)d_in[9];
  const float* w4 = (const float*)d_in[10]; const float* b4 = (const float*)d_in[11];
  const float* w5 = (const float*)d_in[12]; const float* b5 = (const float*)d_in[13];
  const float* w6 = (const float*)d_in[14]; const float* b6 = (const float*)d_in[15];

  u16* ws = (u16*)d_ws;
  u16* X1 = ws;
  u16* X2 = ws + 33554432;
  u16* X3 = ws;
  u16* X4 = ws + 33554432;
  u16* X5 = ws;
  u16* X6 = ws + 33554432;
  u16* f0q = ws + 33554432;      // [2][12][65536][4] f16 (consumed before X2 written)
  u16* f1q = ws + 39845888;
  u16* w1p = ws + 54525952;      // [192][256]
  u16* w2p = w1p + 49152;        // [3][384][160]
  u16* w3p = w2p + 184320;       // [3][384][128]
  u16* w4p = w3p + 147456;       // [3][320][128]
  u16* w5p = w4p + 147456;       // [3][192][96]
  u16* w6p = w5p + 55296;        // [3][128][64] (convr layout, co/rows padded)
  float* bp = (float*)(w6p + 24576);  // 608 f32: b1|b2|b3p|b4|b5|b6p
  u16* zbuf = (u16*)(bp + 608);       // 128 zero bf16 (256B zeros)

  const float* bp1 = bp;
  const float* bp2 = bp + 160;
  const float* bp3 = bp + 288;
  const float* bp4 = bp + 416;
  const float* bp5 = bp + 512;
  const float* bp6 = bp + 576;

  float* flow = (float*)d_out;              // [2][4][256][256]
  float* xout = (float*)d_out + 524288;     // [2][64][256][256]

  prep1_kernel<<<192, 256, 0, stream>>>(w1, w1p);
  prep3s_kernel<128, 160, 128, 384, 160><<<720, 256, 0, stream>>>(w2, w2p);
  prep3s_kernel<112, 128, 128, 384, 128><<<576, 256, 0, stream>>>(w3, w3p);
  prep3s_kernel< 96, 112,  96, 320, 128><<<480, 256, 0, stream>>>(w4, w4p);
  prep3s_kernel< 64,  96,  64, 192,  96><<<216, 256, 0, stream>>>(w5, w5p);
  prep3s_kernel<  4,  64,  32, 128,  64><<< 96, 256, 0, stream>>>(w6, w6p);
  prep_bias_kernel<<<3, 256, 0, stream>>>(b1, b2, b3, b4, b5, b6, bp, zbuf);

  quadize_kernel<<<1024, 256, 0, stream>>>(feat0, feat1, f0q, f1q);
  concat68_kernel<<<2048, 256, 0, stream>>>(lfeat, lflow, X1);
  corr5_kernel<<<1024, 256, 0, stream>>>(f0q, f1q, zbuf, X1);

  // <CI, BM, APLN, KS, OSTRIDE, LRELU, OBF, COF32>  -- full-row, grid 512
  convr32_kernel<256, 160, 192, 1, 160, true,  true,  0><<<512, 256, 0, stream>>>(X1, w1p, bp1, zbuf, X2, nullptr);
  convr32_kernel<160, 128, 384, 3, 128, true,  true,  0><<<512, 256, 0, stream>>>(X2, w2p, bp2, zbuf, X3, nullptr);
  convr32_kernel<128, 128, 384, 3, 128, true,  true,  0><<<512, 256, 0, stream>>>(X3, w3p, bp3, zbuf, X4, nullptr);
  convr32_kernel<128,  96, 320, 3,  96, true,  true,  0><<<512, 256, 0, stream>>>(X4, w4p, bp4, zbuf, X5, nullptr);
  convr32_kernel< 96,  64, 192, 3,  64, true,  true, 64><<<512, 256, 0, stream>>>(X5, w5p, bp5, zbuf, X6, xout);
  convr32_kernel< 64,  32, 128, 3,   1, false, false, 4><<<512, 256, 0, stream>>>(X6, w6p, bp6, zbuf, nullptr, flow);
}

// Round 15
// 291.877 us; speedup vs baseline: 1.0089x; 1.0089x over previous
//
#include <hip/hip_runtime.h>
#include <hip/hip_fp16.h>
#include <cstdint>
#include <cstddef>

// ---------------------------------------------------------------------------
// Optical-flow estimator head, MI355X bf16 MFMA implementation. Round 15:
// convr32 bank-conflict fix. r14's 4.42M conflicts: LDS co-issues the wave's
// two SIMD-32 halves (kg=0/1); with segk=kh*2+kg their slots differed by 1,
// aliasing into half the bank-quad classes. Fix: swap seg bits between
// k-space and slot-space (swapb involution) -> co-issued halves differ by 2
// (r13's conflict-free geometry), data mapping preserved by construction:
// stage k-seg swapb(sp^x) into slot sp; read slot (kg*2+kh)^x which holds
// k-seg kh*2+kg. Everything else byte-identical to round 14.
//
// X layout: NHWC bf16, [pix = b*65536 + h*256 + w][C_stride]
// conv1 K-order permuted: X1 = [feats 0..163 | volume 164..244 | zero 245..255]
// 3x3 weights packed [dy][APLN rows = dx*BM+co, padded][CI].
// ---------------------------------------------------------------------------

using short8 = __attribute__((ext_vector_type(8))) short;
using f32x4  = __attribute__((ext_vector_type(4))) float;
using f32x16 = __attribute__((ext_vector_type(16))) float;
typedef unsigned short u16;

__device__ __forceinline__ u16 rne_bf16(float f) {
  unsigned u = __float_as_uint(f);
  u += 0x7FFFu + ((u >> 16) & 1u);   // round-to-nearest-even
  return (u16)(u >> 16);
}

__device__ __forceinline__ void mfma32(const short8& a, const short8& b, f32x16& c) {
  asm("v_mfma_f32_32x32x16_bf16 %0, %1, %2, %0" : "+v"(c) : "v"(a), "v"(b));
}

__device__ __forceinline__ unsigned pk_f16(float a, float b) {
  unsigned r;
  asm("v_cvt_pkrtz_f16_f32 %0, %1, %2" : "=v"(r) : "v"(a), "v"(b));
  return r;
}

__device__ __forceinline__ void dot2(float& acc, unsigned a, unsigned b) {
  asm("v_dot2_f32_f16 %0, %1, %2, %0" : "+v"(acc) : "v"(a), "v"(b));
}

// async global -> LDS, 16B per lane (wave-uniform LDS base, per-lane source)
__device__ __forceinline__ void gload16(const void* g, void* l) {
  __builtin_amdgcn_global_load_lds(
      (const __attribute__((address_space(1))) unsigned int*)g,
      (__attribute__((address_space(3))) unsigned int*)l, 16, 0, 0);
}

// swap the two bits of a 2-bit value (XOR-linear involution)
__device__ __forceinline__ int swapb(int s) { return ((s & 1) << 1) | (s >> 1); }

// uint2 (4xf16) -> packed 2x bf16 words
__device__ __forceinline__ uint2 quad_to_bf16(uint2 v) {
  __half2 lo = *(__half2*)&v.x, hi = *(__half2*)&v.y;
  uint2 u;
  u.x = (unsigned)rne_bf16(__half2float(lo.x)) | ((unsigned)rne_bf16(__half2float(lo.y)) << 16);
  u.y = (unsigned)rne_bf16(__half2float(hi.x)) | ((unsigned)rne_bf16(__half2float(hi.y)) << 16);
  return u;
}

// ---------------------------------------------------------------------------
// Weight prep
// ---------------------------------------------------------------------------
__global__ __launch_bounds__(256) void prep1_kernel(const float* __restrict__ w1,
                                                    u16* __restrict__ w1p) {
  int idx = blockIdx.x * 256 + threadIdx.x;     // < 192*256
  int co = idx >> 8, cip = idx & 255;
  float v = 0.f;
  if (co < 160 && cip < 245) {
    int ci = (cip < 164) ? (cip + 81) : (cip - 164);
    v = w1[co * 245 + ci];
  }
  w1p[idx] = rne_bf16(v);
}

// 3x3 weights -> [dy][APLN][CIP] bf16, row = dx*BM + co (padded rows/ci zero)
template<int CO, int CIr, int BM, int APLN, int CIP>
__global__ __launch_bounds__(256) void prep3s_kernel(const float* __restrict__ w,
                                                     u16* __restrict__ wp) {
  int idx = blockIdx.x * 256 + threadIdx.x;     // < 3*APLN*CIP
  int ci = idx % CIP; int rest = idx / CIP;
  int row = rest % APLN; int dyp = rest / APLN;
  int dx = row / BM, co = row % BM;
  float v = 0.f;
  if (dx < 3 && co < CO && ci < CIr)
    v = w[(co * CIr + ci) * 9 + dyp * 3 + dx];
  wp[idx] = rne_bf16(v);
}

// padded biases: bp = [b1(160)|b2(128)|b3 pad128|b4(96)|b5(64)|b6 pad32], zbuf zeroed
__global__ __launch_bounds__(256) void prep_bias_kernel(const float* __restrict__ b1,
    const float* __restrict__ b2, const float* __restrict__ b3,
    const float* __restrict__ b4, const float* __restrict__ b5,
    const float* __restrict__ b6,
    float* __restrict__ bp, u16* __restrict__ zbuf) {
  int i = blockIdx.x * 256 + threadIdx.x;       // grid 3 blocks
  if (i < 128) zbuf[i] = 0;
  float v = 0.f;
  if (i < 160) v = b1[i];
  else if (i < 288) v = b2[i - 160];
  else if (i < 416) { int c = i - 288; v = (c < 112) ? b3[c] : 0.f; }
  else if (i < 512) v = b4[i - 416];
  else if (i < 576) v = b5[i - 512];
  else if (i < 608) { int c = i - 576; v = (c < 4) ? b6[c] : 0.f; }
  else return;
  bp[i] = v;
}

// ---------------------------------------------------------------------------
// quadize: f0/f1 NCHW f32 -> f16 quad planes [b][12][hw][4ch]. Register-only.
// ---------------------------------------------------------------------------
__global__ __launch_bounds__(256) void quadize_kernel(const float* __restrict__ f0,
                                                      const float* __restrict__ f1,
                                                      u16* __restrict__ f0q,
                                                      u16* __restrict__ f1q) {
  const int bid = blockIdx.x;
  const int qh = bid >> 9;             // 0/1
  const int b = (bid >> 8) & 1;
  const int h = bid & 255;
  const int hw = (h << 8) + threadIdx.x;
  const float* s0 = f0 + (((size_t)(b * 48 + qh * 24)) << 16) + hw;
  const float* s1 = f1 + (((size_t)(b * 48 + qh * 24)) << 16) + hw;
  u16* d0 = f0q + (((size_t)((b * 12 + qh * 6) << 16)) + hw) * 4;
  u16* d1 = f1q + (((size_t)((b * 12 + qh * 6) << 16)) + hw) * 4;
#pragma unroll
  for (int q = 0; q < 6; ++q) {
    uint2 u;
    u.x = pk_f16(s0[((size_t)(4 * q)) << 16],     s0[((size_t)(4 * q + 1)) << 16]);
    u.y = pk_f16(s0[((size_t)(4 * q + 2)) << 16], s0[((size_t)(4 * q + 3)) << 16]);
    *(uint2*)(d0 + (size_t)q * 262144) = u;
    uint2 v;
    v.x = pk_f16(s1[((size_t)(4 * q)) << 16],     s1[((size_t)(4 * q + 1)) << 16]);
    v.y = pk_f16(s1[((size_t)(4 * q + 2)) << 16], s1[((size_t)(4 * q + 3)) << 16]);
    *(uint2*)(d1 + (size_t)q * 262144) = v;
  }
}

// ---------------------------------------------------------------------------
// concat68: lf/lfl -> X1 ch 96..163.
// ---------------------------------------------------------------------------
__global__ __launch_bounds__(256) void concat68_kernel(const float* __restrict__ lf,
                                                       const float* __restrict__ lfl,
                                                       u16* __restrict__ X1) {
  __shared__ float s[16][68];
  const int t = threadIdx.x;
  const size_t px0 = (size_t)blockIdx.x * 64;
  const int b = blockIdx.x >> 10;
  const int hw0 = (blockIdx.x & 1023) * 64;

#pragma unroll 1
  for (int cc = 0; cc < 5; ++cc) {
    __syncthreads();
    {
      int px = t & 63, cg = t >> 6;
#pragma unroll
      for (int r = 0; r < 4; ++r) {
        int cl = cg * 4 + r;
        int c = cc * 16 + cl;           // 0..79 (68 used)
        int hw = hw0 + px;
        float v = 0.f;
        if (c < 64)       v = lf[(((size_t)(b * 64 + c)) << 16) + hw];
        else if (c < 68)  v = lfl[(((size_t)(b * 4 + (c - 64))) << 16) + hw];
        s[cl][px] = v;
      }
    }
    __syncthreads();
    {
      int px = t >> 2, g = t & 3;
      int cbase = cc * 16 + g * 4;
      if (cbase < 68) {
        ushort4 u;
        u.x = rne_bf16(s[g * 4 + 0][px]);
        u.y = rne_bf16(s[g * 4 + 1][px]);
        u.z = rne_bf16(s[g * 4 + 2][px]);
        u.w = rne_bf16(s[g * 4 + 3][px]);
        *(ushort4*)(X1 + (px0 + px) * 256 + 96 + cbase) = u;
      }
    }
  }
}

// ---------------------------------------------------------------------------
// corr5 (round-7 design, unchanged): async-staged windowed correlation.
// ---------------------------------------------------------------------------
template<int NDY>
__device__ __forceinline__ void corr_acc(const uint2* __restrict__ wb,
                                         const unsigned* __restrict__ f0p,
                                         float* __restrict__ cv,
                                         int row, int col, int dy0) {
#pragma unroll
  for (int d = 0; d < NDY; ++d) {
    const int r = row + dy0 + d;
#pragma unroll
    for (int q = 0; q < 3; ++q) {
      const uint2* base = wb + (q * 10 + r) * 80 + (col + 4);
#pragma unroll
      for (int dx = 0; dx < 9; ++dx) {
        const uint2 v = base[dx];
        dot2(cv[d * 9 + dx], v.x, f0p[2 * q]);
        dot2(cv[d * 9 + dx], v.y, f0p[2 * q + 1]);
      }
    }
  }
}

__global__ __launch_bounds__(256, 4) void corr5_kernel(const u16* __restrict__ f0q,
                                                       const u16* __restrict__ f1q,
                                                       const u16* __restrict__ zbuf,
                                                       u16* __restrict__ X1) {
  __shared__ char wlds[2][20480];        // [3q][10r][80c] x 8B = 19.2KB + pad
  const int bid = blockIdx.x;
  const int swz = (bid & 7) * 128 + (bid >> 3);   // XCD-contiguous, bijective
  const int b = swz >> 9, rest = swz & 511;
  const int hp = rest >> 2, ct = rest & 3;
  const int h0 = hp << 1, w0 = ct << 6;
  const int tid = threadIdx.x, lane = tid & 63, wv = tid >> 6;
  const int half = wv >> 1, row = wv & 1, col = lane;
  const int pixhw = ((h0 + row) << 8) + (w0 + col);
  const size_t pix = ((size_t)b << 16) + pixhw;

  const u16* srcp[5];
  bool okf[5];
#pragma unroll
  for (int ru = 0; ru < 5; ++ru) {
    int u = ru * 256 + tid;
    int uq = u / 400;                    // 0..2 real, 3 = pad
    int rem = u - uq * 400;
    int r = rem / 40, cu = rem - r * 40;
    int hin = h0 + r - 4;
    int wpx = w0 - 8 + 2 * cu;           // even
    bool ok = (u < 1200) && ((unsigned)hin < 256u) && ((unsigned)wpx < 256u);
    okf[ru] = ok;
    srcp[ru] = ok ? (f1q + (((size_t)((b * 12 + uq) << 16) + (hin << 8) + wpx) << 2))
                  : zbuf;
  }

  float cv[45];
#pragma unroll
  for (int t = 0; t < 45; ++t) cv[t] = 0.f;

#pragma unroll
  for (int ru = 0; ru < 5; ++ru)
    gload16(srcp[ru], &wlds[0][ru * 4096 + wv * 1024]);

#pragma unroll 1
  for (int cc = 0; cc < 4; ++cc) {
    __syncthreads();
    if (cc < 3) {
#pragma unroll
      for (int ru = 0; ru < 5; ++ru) {
        const u16* s = okf[ru] ? (srcp[ru] + (size_t)(cc + 1) * 786432) : zbuf;
        gload16(s, &wlds[(cc + 1) & 1][ru * 4096 + wv * 1024]);
      }
    }
    const uint2* wb = (const uint2*)&wlds[cc & 1][0];

    const u16* f0base = f0q + (((size_t)((b * 12 + cc * 3) << 16) + pixhw) << 2);
    uint2 q0 = *(const uint2*)(f0base);
    uint2 q1 = *(const uint2*)(f0base + 262144);
    uint2 q2 = *(const uint2*)(f0base + 524288);
    unsigned f0p[6] = {q0.x, q0.y, q1.x, q1.y, q2.x, q2.y};

    {
      u16* dst0 = X1 + pix * 256 + cc * 12;
      *(uint2*)(dst0)     = quad_to_bf16(q0);
      *(uint2*)(dst0 + 4) = quad_to_bf16(q1);
      *(uint2*)(dst0 + 8) = quad_to_bf16(q2);
    }
    {
      u16* dst1 = X1 + pix * 256 + 48 + cc * 12;
#pragma unroll
      for (int q = 0; q < 3; ++q) {
        uint2 v = wb[(q * 10 + row + 4) * 80 + (col + 8)];
        *(uint2*)(dst1 + 4 * q) = quad_to_bf16(v);
      }
    }
    if (half == 0) corr_acc<4>(wb, f0p, cv, row, col, 0);
    else           corr_acc<5>(wb, f0p, cv, row, col, 4);
  }

  u16* dst = X1 + pix * 256;
  const float sc = 1.0f / 48.0f;
  if (half == 0) {
#pragma unroll
    for (int qq = 0; qq < 9; ++qq) {
      u16 e[4];
#pragma unroll
      for (int j = 0; j < 4; ++j) {
        float v = cv[qq * 4 + j] * sc;
        v = v > 0.f ? v : 0.1f * v;
        e[j] = rne_bf16(v);
      }
      uint2 u;
      u.x = (unsigned)e[0] | ((unsigned)e[1] << 16);
      u.y = (unsigned)e[2] | ((unsigned)e[3] << 16);
      *(uint2*)(dst + 164 + qq * 4) = u;
    }
  } else {
#pragma unroll
    for (int qq = 0; qq < 14; ++qq) {
      u16 e[4];
#pragma unroll
      for (int j = 0; j < 4; ++j) {
        int t = qq * 4 + j;
        float v = 0.f;
        if (t < 45) {
          v = cv[t] * sc;
          v = v > 0.f ? v : 0.1f * v;
        }
        e[j] = rne_bf16(v);
      }
      uint2 u;
      u.x = (unsigned)e[0] | ((unsigned)e[1] << 16);
      u.y = (unsigned)e[2] | ((unsigned)e[3] << 16);
      *(uint2*)(dst + 200 + qq * 4) = u;
    }
  }
}

// ---------------------------------------------------------------------------
// Full-row merged-tap implicit-GEMM conv, 32x32x16 MFMA (round 15).
// Block = (batch, row h) x 256 px. 4 waves 1m x 4n: wave = BM co x 64 px.
// Swizzle: LDS slot sp at row holds k-segment swapb(sp ^ ((row>>1)&3));
// lane (kg) at iteration kh reads slot (kg*2+kh) ^ ((row>>1)&3), which holds
// k-segment kh*2+kg — co-issued SIMD-halves' slots differ by 2 (conflict-free).
// C/D: col=lane&31, row=(reg&3)+8*(reg>>2)+4*(lane>>5) (m74/m101-verified).
// ---------------------------------------------------------------------------
template<int CI, int BM, int APLN, int KS, int OSTRIDE, bool LRELU, bool OBF, int COF32>
__global__ __launch_bounds__(256, 2) void convr32_kernel(const u16* __restrict__ Xin,
    const u16* __restrict__ Wp, const float* __restrict__ bias,
    const u16* __restrict__ zbuf, u16* __restrict__ Xout,
    float* __restrict__ outF) {
  constexpr int NCH = CI / 32;
  constexpr int NDX = (KS == 3) ? 3 : 1;
  constexpr int HALO = (KS == 3) ? 2 : 0;
  constexpr int AROUNDS = APLN / 64;
  constexpr int BROUNDS = (KS == 3) ? 5 : 4;   // 320 / 256 px-slots
  constexpr int BPXMAX = 256 + 2 * HALO;       // valid slot count
  constexpr int MF32 = BM / 32;
  constexpr int AELEMS = AROUNDS * 2048;       // u16
  constexpr int NPH = NDX * NCH;
  __shared__ u16 lds[AELEMS + BROUNDS * 2048];

  const int tid = threadIdx.x;
  const int lane = tid & 63, wn = tid >> 6;    // 4 waves, each 64 px
  const int bid = blockIdx.x;
  const int swz = (bid & 7) * 64 + (bid >> 3); // 512 blocks, bijective
  const int bi = swz >> 8;
  const int h = swz & 255;
  const int l31 = lane & 31, kg = lane >> 5;   // k-group (8-elem half)

  size_t aofs[AROUNDS];
#pragma unroll
  for (int r = 0; r < AROUNDS; ++r) {
    int slot = r * 256 + tid;
    int row = slot >> 2, sp = slot & 3;
    int seg = swapb(sp ^ ((row >> 1) & 3));    // k-segment stored in slot sp
    aofs[r] = (size_t)row * CI + seg * 8;
  }
  size_t bofs[BROUNDS];
  bool bcolv[BROUNDS];
#pragma unroll
  for (int r = 0; r < BROUNDS; ++r) {
    int slot = r * 256 + tid;
    int pxl = slot >> 2, sp = slot & 3;
    int seg = swapb(sp ^ ((pxl >> 1) & 3));
    int px = pxl - HALO;
    bcolv[r] = ((unsigned)px < 256u) && (pxl < BPXMAX);
    bofs[r] = (size_t)px * CI + seg * 8;
  }

  f32x16 acc[MF32][2];
#pragma unroll
  for (int m = 0; m < MF32; ++m)
#pragma unroll
    for (int n = 0; n < 2; ++n)
#pragma unroll
      for (int e = 0; e < 16; ++e) acc[m][n][e] = 0.f;

  int dy = 0, c = 0;
#pragma unroll 1
  for (int ph = 0; ph < NPH; ++ph) {
    __syncthreads();                 // protect LDS from prev phase readers
    const u16* Wph = Wp + ((size_t)dy * APLN) * CI + c * 32;
#pragma unroll
    for (int r = 0; r < AROUNDS; ++r)
      gload16(Wph + aofs[r], &lds[r * 2048 + wn * 512]);
    const int hin = (KS == 3) ? (h + dy - 1) : h;
    const bool rv = (unsigned)hin < 256u;
    const u16* Brow = Xin + ((size_t)((bi << 8) + (rv ? hin : 0)) << 8) * CI + c * 32;
#pragma unroll
    for (int r = 0; r < BROUNDS; ++r) {
      const u16* src = (rv && bcolv[r]) ? (Brow + bofs[r]) : zbuf;
      gload16(src, &lds[AELEMS + r * 2048 + wn * 512]);
    }
    __syncthreads();                 // staging complete

#pragma unroll
    for (int dx = 0; dx < NDX; ++dx) {
#pragma unroll
      for (int kh = 0; kh < 2; ++kh) {
        const int segk = kg * 2 + kh;          // slot selector = swapb(k-seg)
        short8 bfr[2];
#pragma unroll
        for (int n = 0; n < 2; ++n) {
          int p = wn * 64 + n * 32 + l31;
          int pxl = (KS == 3) ? (p + dx + 1) : p;   // slot = px + HALO
          int ba = (AELEMS * 2) + pxl * 64 + ((segk ^ ((pxl >> 1) & 3)) << 4);
          bfr[n] = *(const short8*)((const char*)lds + ba);
        }
        short8 afr[MF32];
#pragma unroll
        for (int m = 0; m < MF32; ++m) {
          int row = dx * BM + m * 32 + l31;
          int aa = row * 64 + ((segk ^ ((row >> 1) & 3)) << 4);
          afr[m] = *(const short8*)((const char*)lds + aa);
        }
#pragma unroll
        for (int m = 0; m < MF32; ++m)
#pragma unroll
          for (int n = 0; n < 2; ++n) mfma32(afr[m], bfr[n], acc[m][n]);
      }
    }
    if (++c == NCH) { c = 0; ++dy; }
  }
  asm volatile("s_nop 7\n\ts_nop 7");   // MFMA -> VALU hazard insurance

  const size_t pixbase = ((size_t)((bi << 8) + h)) << 8;
#pragma unroll
  for (int m = 0; m < MF32; ++m) {
#pragma unroll
    for (int n = 0; n < 2; ++n) {
      const int px = wn * 64 + n * 32 + l31;
      f32x16 v = acc[m][n];
#pragma unroll
      for (int q = 0; q < 4; ++q) {
        const int co = m * 32 + q * 8 + kg * 4;   // + (0..3) via reg&3
        float t[4];
#pragma unroll
        for (int r = 0; r < 4; ++r) {
          float x = v[q * 4 + r] + bias[co + r];
          if (LRELU) x = x > 0.f ? x : 0.1f * x;
          t[r] = x;
        }
        if (OBF) {
          ushort4 u;
          u.x = rne_bf16(t[0]); u.y = rne_bf16(t[1]);
          u.z = rne_bf16(t[2]); u.w = rne_bf16(t[3]);
          *(ushort4*)(Xout + (pixbase + px) * OSTRIDE + co) = u;
        }
        if (COF32 > 0) {
#pragma unroll
          for (int r = 0; r < 4; ++r) {
            int cch = co + r;
            if (cch < COF32)
              outF[(((size_t)bi * COF32 + cch) << 16) + (h << 8) + px] = t[r];
          }
        }
      }
    }
  }
}

// ---------------------------------------------------------------------------
extern "C" void kernel_launch(void* const* d_in, const int* in_sizes, int n_in,
                              void* d_out, int out_size, void* d_ws, size_t ws_size,
                              hipStream_t stream) {
  const float* feat0 = (const float*)d_in[0];
  const float* feat1 = (const float*)d_in[1];
  const float* lfeat = (const float*)d_in[2];
  const float* lflow = (const float*)d_in[3];
  const float* w1 = (const float*)d_in[4];  const float* b1 = (const float*)d_in[5];
  const float* w2 = (const float*)d_in[6];  const float* b2 = (const float*)d_in[7];
  const float* w3 = (const float*)d_in[8];  const float* b3 = (const float*)d_in[9];
  const float* w4 = (const float*)d_in[10]; const float* b4 = (const float*)d_in[11];
  const float* w5 = (const float*)d_in[12]; const float* b5 = (const float*)d_in[13];
  const float* w6 = (const float*)d_in[14]; const float* b6 = (const float*)d_in[15];

  u16* ws = (u16*)d_ws;
  u16* X1 = ws;
  u16* X2 = ws + 33554432;
  u16* X3 = ws;
  u16* X4 = ws + 33554432;
  u16* X5 = ws;
  u16* X6 = ws + 33554432;
  u16* f0q = ws + 33554432;      // [2][12][65536][4] f16 (consumed before X2 written)
  u16* f1q = ws + 39845888;
  u16* w1p = ws + 54525952;      // [192][256]
  u16* w2p = w1p + 49152;        // [3][384][160]
  u16* w3p = w2p + 184320;       // [3][384][128]
  u16* w4p = w3p + 147456;       // [3][320][128]
  u16* w5p = w4p + 147456;       // [3][192][96]
  u16* w6p = w5p + 55296;        // [3][128][64] (convr layout, co/rows padded)
  float* bp = (float*)(w6p + 24576);  // 608 f32: b1|b2|b3p|b4|b5|b6p
  u16* zbuf = (u16*)(bp + 608);       // 128 zero bf16 (256B zeros)

  const float* bp1 = bp;
  const float* bp2 = bp + 160;
  const float* bp3 = bp + 288;
  const float* bp4 = bp + 416;
  const float* bp5 = bp + 512;
  const float* bp6 = bp + 576;

  float* flow = (float*)d_out;              // [2][4][256][256]
  float* xout = (float*)d_out + 524288;     // [2][64][256][256]

  prep1_kernel<<<192, 256, 0, stream>>>(w1, w1p);
  prep3s_kernel<128, 160, 128, 384, 160><<<720, 256, 0, stream>>>(w2, w2p);
  prep3s_kernel<112, 128, 128, 384, 128><<<576, 256, 0, stream>>>(w3, w3p);
  prep3s_kernel< 96, 112,  96, 320, 128><<<480, 256, 0, stream>>>(w4, w4p);
  prep3s_kernel< 64,  96,  64, 192,  96><<<216, 256, 0, stream>>>(w5, w5p);
  prep3s_kernel<  4,  64,  32, 128,  64><<< 96, 256, 0, stream>>>(w6, w6p);
  prep_bias_kernel<<<3, 256, 0, stream>>>(b1, b2, b3, b4, b5, b6, bp, zbuf);

  quadize_kernel<<<1024, 256, 0, stream>>>(feat0, feat1, f0q, f1q);
  concat68_kernel<<<2048, 256, 0, stream>>>(lfeat, lflow, X1);
  corr5_kernel<<<1024, 256, 0, stream>>>(f0q, f1q, zbuf, X1);

  // <CI, BM, APLN, KS, OSTRIDE, LRELU, OBF, COF32>  -- full-row, grid 512
  convr32_kernel<256, 160, 192, 1, 160, true,  true,  0><<<512, 256, 0, stream>>>(X1, w1p, bp1, zbuf, X2, nullptr);
  convr32_kernel<160, 128, 384, 3, 128, true,  true,  0><<<512, 256, 0, stream>>>(X2, w2p, bp2, zbuf, X3, nullptr);
  convr32_kernel<128, 128, 384, 3, 128, true,  true,  0><<<512, 256, 0, stream>>>(X3, w3p, bp3, zbuf, X4, nullptr);
  convr32_kernel<128,  96, 320, 3,  96, true,  true,  0><<<512, 256, 0, stream>>>(X4, w4p, bp4, zbuf, X5, nullptr);
  convr32_kernel< 96,  64, 192, 3,  64, true,  true, 64><<<512, 256, 0, stream>>>(X5, w5p, bp5, zbuf, X6, xout);
  convr32_kernel< 64,  32, 128, 3,   1, false, false, 4><<<512, 256, 0, stream>>>(X6, w6p, bp6, zbuf, nullptr, flow);
}

// Round 16
// 282.431 us; speedup vs baseline: 1.0427x; 1.0334x over previous
//
#include <hip/hip_runtime.h>
#include <hip/hip_fp16.h>
#include <cstdint>
#include <cstddef>

// ---------------------------------------------------------------------------
// Optical-flow estimator head, MI355X bf16 MFMA implementation. Round 16:
// byte-for-byte revert to the round-13 kernel (best measured: 282.6us).
// r14/r15's 32x32x16 MFMA experiment is structurally dead: with 64B LDS rows
// a 16B slot has only 8 bank-quad classes (row&1 x slot), and the 32-row
// fragment reads force 4 lanes/class (intrinsic 4-way conflict, 4.42M/disp,
// invariant under slot permutation). 16x16x32 reads 16 rows -> 2/class, free.
// Structure ceiling evidence: r8 dbuf-vmcnt neutral, r11 anti-phase null,
// r12 8-phase -35%, r14/r15 32x32 -9%. The 2-barrier convr at ~37% MfmaUtil
// is this op-shape's practical ceiling.
//
// X layout: NHWC bf16, [pix = b*65536 + h*256 + w][C_stride]
// conv1 K-order permuted: X1 = [feats 0..163 | volume 164..244 | zero 245..255]
// 3x3 weights packed [dy][APLN rows = dx*BM+co, padded][CI].
// ---------------------------------------------------------------------------

using short8 = __attribute__((ext_vector_type(8))) short;
using f32x4  = __attribute__((ext_vector_type(4))) float;
typedef unsigned short u16;

__device__ __forceinline__ u16 rne_bf16(float f) {
  unsigned u = __float_as_uint(f);
  u += 0x7FFFu + ((u >> 16) & 1u);   // round-to-nearest-even
  return (u16)(u >> 16);
}

__device__ __forceinline__ void mfma16(const short8& a, const short8& b, f32x4& c) {
  asm("v_mfma_f32_16x16x32_bf16 %0, %1, %2, %0" : "+v"(c) : "v"(a), "v"(b));
}

__device__ __forceinline__ unsigned pk_f16(float a, float b) {
  unsigned r;
  asm("v_cvt_pkrtz_f16_f32 %0, %1, %2" : "=v"(r) : "v"(a), "v"(b));
  return r;
}

__device__ __forceinline__ void dot2(float& acc, unsigned a, unsigned b) {
  asm("v_dot2_f32_f16 %0, %1, %2, %0" : "+v"(acc) : "v"(a), "v"(b));
}

// async global -> LDS, 16B per lane (wave-uniform LDS base, per-lane source)
__device__ __forceinline__ void gload16(const void* g, void* l) {
  __builtin_amdgcn_global_load_lds(
      (const __attribute__((address_space(1))) unsigned int*)g,
      (__attribute__((address_space(3))) unsigned int*)l, 16, 0, 0);
}

// uint2 (4xf16) -> packed 2x bf16 words
__device__ __forceinline__ uint2 quad_to_bf16(uint2 v) {
  __half2 lo = *(__half2*)&v.x, hi = *(__half2*)&v.y;
  uint2 u;
  u.x = (unsigned)rne_bf16(__half2float(lo.x)) | ((unsigned)rne_bf16(__half2float(lo.y)) << 16);
  u.y = (unsigned)rne_bf16(__half2float(hi.x)) | ((unsigned)rne_bf16(__half2float(hi.y)) << 16);
  return u;
}

// ---------------------------------------------------------------------------
// Weight prep
// ---------------------------------------------------------------------------
__global__ __launch_bounds__(256) void prep1_kernel(const float* __restrict__ w1,
                                                    u16* __restrict__ w1p) {
  int idx = blockIdx.x * 256 + threadIdx.x;     // < 192*256
  int co = idx >> 8, cip = idx & 255;
  float v = 0.f;
  if (co < 160 && cip < 245) {
    int ci = (cip < 164) ? (cip + 81) : (cip - 164);
    v = w1[co * 245 + ci];
  }
  w1p[idx] = rne_bf16(v);
}

// 3x3 weights -> [dy][APLN][CIP] bf16, row = dx*BM + co (padded rows/ci zero)
template<int CO, int CIr, int BM, int APLN, int CIP>
__global__ __launch_bounds__(256) void prep3s_kernel(const float* __restrict__ w,
                                                     u16* __restrict__ wp) {
  int idx = blockIdx.x * 256 + threadIdx.x;     // < 3*APLN*CIP
  int ci = idx % CIP; int rest = idx / CIP;
  int row = rest % APLN; int dyp = rest / APLN;
  int dx = row / BM, co = row % BM;
  float v = 0.f;
  if (dx < 3 && co < CO && ci < CIr)
    v = w[(co * CIr + ci) * 9 + dyp * 3 + dx];
  wp[idx] = rne_bf16(v);
}

// padded biases: bp = [b1(160)|b2(128)|b3 pad128|b4(96)|b5(64)|b6 pad32], zbuf zeroed
__global__ __launch_bounds__(256) void prep_bias_kernel(const float* __restrict__ b1,
    const float* __restrict__ b2, const float* __restrict__ b3,
    const float* __restrict__ b4, const float* __restrict__ b5,
    const float* __restrict__ b6,
    float* __restrict__ bp, u16* __restrict__ zbuf) {
  int i = blockIdx.x * 256 + threadIdx.x;       // grid 3 blocks
  if (i < 128) zbuf[i] = 0;
  float v = 0.f;
  if (i < 160) v = b1[i];
  else if (i < 288) v = b2[i - 160];
  else if (i < 416) { int c = i - 288; v = (c < 112) ? b3[c] : 0.f; }
  else if (i < 512) v = b4[i - 416];
  else if (i < 576) v = b5[i - 512];
  else if (i < 608) { int c = i - 576; v = (c < 4) ? b6[c] : 0.f; }
  else return;
  bp[i] = v;
}

// ---------------------------------------------------------------------------
// quadize: f0/f1 NCHW f32 -> f16 quad planes [b][12][hw][4ch]. Register-only.
// ---------------------------------------------------------------------------
__global__ __launch_bounds__(256) void quadize_kernel(const float* __restrict__ f0,
                                                      const float* __restrict__ f1,
                                                      u16* __restrict__ f0q,
                                                      u16* __restrict__ f1q) {
  const int bid = blockIdx.x;
  const int qh = bid >> 9;             // 0/1
  const int b = (bid >> 8) & 1;
  const int h = bid & 255;
  const int hw = (h << 8) + threadIdx.x;
  const float* s0 = f0 + (((size_t)(b * 48 + qh * 24)) << 16) + hw;
  const float* s1 = f1 + (((size_t)(b * 48 + qh * 24)) << 16) + hw;
  u16* d0 = f0q + (((size_t)((b * 12 + qh * 6) << 16)) + hw) * 4;
  u16* d1 = f1q + (((size_t)((b * 12 + qh * 6) << 16)) + hw) * 4;
#pragma unroll
  for (int q = 0; q < 6; ++q) {
    uint2 u;
    u.x = pk_f16(s0[((size_t)(4 * q)) << 16],     s0[((size_t)(4 * q + 1)) << 16]);
    u.y = pk_f16(s0[((size_t)(4 * q + 2)) << 16], s0[((size_t)(4 * q + 3)) << 16]);
    *(uint2*)(d0 + (size_t)q * 262144) = u;
    uint2 v;
    v.x = pk_f16(s1[((size_t)(4 * q)) << 16],     s1[((size_t)(4 * q + 1)) << 16]);
    v.y = pk_f16(s1[((size_t)(4 * q + 2)) << 16], s1[((size_t)(4 * q + 3)) << 16]);
    *(uint2*)(d1 + (size_t)q * 262144) = v;
  }
}

// ---------------------------------------------------------------------------
// concat68: lf/lfl -> X1 ch 96..163.
// ---------------------------------------------------------------------------
__global__ __launch_bounds__(256) void concat68_kernel(const float* __restrict__ lf,
                                                       const float* __restrict__ lfl,
                                                       u16* __restrict__ X1) {
  __shared__ float s[16][68];
  const int t = threadIdx.x;
  const size_t px0 = (size_t)blockIdx.x * 64;
  const int b = blockIdx.x >> 10;
  const int hw0 = (blockIdx.x & 1023) * 64;

#pragma unroll 1
  for (int cc = 0; cc < 5; ++cc) {
    __syncthreads();
    {
      int px = t & 63, cg = t >> 6;
#pragma unroll
      for (int r = 0; r < 4; ++r) {
        int cl = cg * 4 + r;
        int c = cc * 16 + cl;           // 0..79 (68 used)
        int hw = hw0 + px;
        float v = 0.f;
        if (c < 64)       v = lf[(((size_t)(b * 64 + c)) << 16) + hw];
        else if (c < 68)  v = lfl[(((size_t)(b * 4 + (c - 64))) << 16) + hw];
        s[cl][px] = v;
      }
    }
    __syncthreads();
    {
      int px = t >> 2, g = t & 3;
      int cbase = cc * 16 + g * 4;
      if (cbase < 68) {
        ushort4 u;
        u.x = rne_bf16(s[g * 4 + 0][px]);
        u.y = rne_bf16(s[g * 4 + 1][px]);
        u.z = rne_bf16(s[g * 4 + 2][px]);
        u.w = rne_bf16(s[g * 4 + 3][px]);
        *(ushort4*)(X1 + (px0 + px) * 256 + 96 + cbase) = u;
      }
    }
  }
}

// ---------------------------------------------------------------------------
// corr5 (round-7 design, unchanged): async-staged windowed correlation.
// ---------------------------------------------------------------------------
template<int NDY>
__device__ __forceinline__ void corr_acc(const uint2* __restrict__ wb,
                                         const unsigned* __restrict__ f0p,
                                         float* __restrict__ cv,
                                         int row, int col, int dy0) {
#pragma unroll
  for (int d = 0; d < NDY; ++d) {
    const int r = row + dy0 + d;
#pragma unroll
    for (int q = 0; q < 3; ++q) {
      const uint2* base = wb + (q * 10 + r) * 80 + (col + 4);
#pragma unroll
      for (int dx = 0; dx < 9; ++dx) {
        const uint2 v = base[dx];
        dot2(cv[d * 9 + dx], v.x, f0p[2 * q]);
        dot2(cv[d * 9 + dx], v.y, f0p[2 * q + 1]);
      }
    }
  }
}

__global__ __launch_bounds__(256, 4) void corr5_kernel(const u16* __restrict__ f0q,
                                                       const u16* __restrict__ f1q,
                                                       const u16* __restrict__ zbuf,
                                                       u16* __restrict__ X1) {
  __shared__ char wlds[2][20480];        // [3q][10r][80c] x 8B = 19.2KB + pad
  const int bid = blockIdx.x;
  const int swz = (bid & 7) * 128 + (bid >> 3);   // XCD-contiguous, bijective
  const int b = swz >> 9, rest = swz & 511;
  const int hp = rest >> 2, ct = rest & 3;
  const int h0 = hp << 1, w0 = ct << 6;
  const int tid = threadIdx.x, lane = tid & 63, wv = tid >> 6;
  const int half = wv >> 1, row = wv & 1, col = lane;
  const int pixhw = ((h0 + row) << 8) + (w0 + col);
  const size_t pix = ((size_t)b << 16) + pixhw;

  const u16* srcp[5];
  bool okf[5];
#pragma unroll
  for (int ru = 0; ru < 5; ++ru) {
    int u = ru * 256 + tid;
    int uq = u / 400;                    // 0..2 real, 3 = pad
    int rem = u - uq * 400;
    int r = rem / 40, cu = rem - r * 40;
    int hin = h0 + r - 4;
    int wpx = w0 - 8 + 2 * cu;           // even
    bool ok = (u < 1200) && ((unsigned)hin < 256u) && ((unsigned)wpx < 256u);
    okf[ru] = ok;
    srcp[ru] = ok ? (f1q + (((size_t)((b * 12 + uq) << 16) + (hin << 8) + wpx) << 2))
                  : zbuf;
  }

  float cv[45];
#pragma unroll
  for (int t = 0; t < 45; ++t) cv[t] = 0.f;

#pragma unroll
  for (int ru = 0; ru < 5; ++ru)
    gload16(srcp[ru], &wlds[0][ru * 4096 + wv * 1024]);

#pragma unroll 1
  for (int cc = 0; cc < 4; ++cc) {
    __syncthreads();
    if (cc < 3) {
#pragma unroll
      for (int ru = 0; ru < 5; ++ru) {
        const u16* s = okf[ru] ? (srcp[ru] + (size_t)(cc + 1) * 786432) : zbuf;
        gload16(s, &wlds[(cc + 1) & 1][ru * 4096 + wv * 1024]);
      }
    }
    const uint2* wb = (const uint2*)&wlds[cc & 1][0];

    const u16* f0base = f0q + (((size_t)((b * 12 + cc * 3) << 16) + pixhw) << 2);
    uint2 q0 = *(const uint2*)(f0base);
    uint2 q1 = *(const uint2*)(f0base + 262144);
    uint2 q2 = *(const uint2*)(f0base + 524288);
    unsigned f0p[6] = {q0.x, q0.y, q1.x, q1.y, q2.x, q2.y};

    {
      u16* dst0 = X1 + pix * 256 + cc * 12;
      *(uint2*)(dst0)     = quad_to_bf16(q0);
      *(uint2*)(dst0 + 4) = quad_to_bf16(q1);
      *(uint2*)(dst0 + 8) = quad_to_bf16(q2);
    }
    {
      u16* dst1 = X1 + pix * 256 + 48 + cc * 12;
#pragma unroll
      for (int q = 0; q < 3; ++q) {
        uint2 v = wb[(q * 10 + row + 4) * 80 + (col + 8)];
        *(uint2*)(dst1 + 4 * q) = quad_to_bf16(v);
      }
    }
    if (half == 0) corr_acc<4>(wb, f0p, cv, row, col, 0);
    else           corr_acc<5>(wb, f0p, cv, row, col, 4);
  }

  u16* dst = X1 + pix * 256;
  const float sc = 1.0f / 48.0f;
  if (half == 0) {
#pragma unroll
    for (int qq = 0; qq < 9; ++qq) {
      u16 e[4];
#pragma unroll
      for (int j = 0; j < 4; ++j) {
        float v = cv[qq * 4 + j] * sc;
        v = v > 0.f ? v : 0.1f * v;
        e[j] = rne_bf16(v);
      }
      uint2 u;
      u.x = (unsigned)e[0] | ((unsigned)e[1] << 16);
      u.y = (unsigned)e[2] | ((unsigned)e[3] << 16);
      *(uint2*)(dst + 164 + qq * 4) = u;
    }
  } else {
#pragma unroll
    for (int qq = 0; qq < 14; ++qq) {
      u16 e[4];
#pragma unroll
      for (int j = 0; j < 4; ++j) {
        int t = qq * 4 + j;
        float v = 0.f;
        if (t < 45) {
          v = cv[t] * sc;
          v = v > 0.f ? v : 0.1f * v;
        }
        e[j] = rne_bf16(v);
      }
      uint2 u;
      u.x = (unsigned)e[0] | ((unsigned)e[1] << 16);
      u.y = (unsigned)e[2] | ((unsigned)e[3] << 16);
      *(uint2*)(dst + 200 + qq * 4) = u;
    }
  }
}

// ---------------------------------------------------------------------------
// Full-row merged-tap implicit-GEMM conv (round-9/10 design, unchanged).
// Block = (batch, row h) x 256 px. 4 waves 2m x 2n. Single-buffered,
// 2 barriers/phase. LDS XOR-swizzled via pre-swizzled gather sources.
// ---------------------------------------------------------------------------
template<int CI, int BM, int APLN, int KS, int OSTRIDE, bool LRELU, bool OBF, int COF32>
__global__ __launch_bounds__(256, 2) void convr_kernel(const u16* __restrict__ Xin,
    const u16* __restrict__ Wp, const float* __restrict__ bias,
    const u16* __restrict__ zbuf, u16* __restrict__ Xout,
    float* __restrict__ outF) {
  constexpr int NCH = CI / 32;
  constexpr int NDX = (KS == 3) ? 3 : 1;
  constexpr int HALO = (KS == 3) ? 2 : 0;
  constexpr int AROUNDS = APLN / 64;
  constexpr int BROUNDS = (KS == 3) ? 5 : 4;   // 320 / 256 px-slots
  constexpr int BPXMAX = 256 + 2 * HALO;       // valid slot count
  constexpr int MF = BM / 32;
  constexpr int AELEMS = AROUNDS * 2048;       // u16
  constexpr int NPH = NDX * NCH;
  __shared__ u16 lds[AELEMS + BROUNDS * 2048];

  const int tid = threadIdx.x;
  const int lane = tid & 63, wv = tid >> 6;
  const int wm = wv >> 1, wn = wv & 1;
  const int bid = blockIdx.x;
  const int swz = (bid & 7) * 64 + (bid >> 3);  // 512 blocks, bijective
  const int bi = swz >> 8;
  const int h = swz & 255;
  const int l15 = lane & 15, segr = lane >> 4;

  size_t aofs[AROUNDS];
#pragma unroll
  for (int r = 0; r < AROUNDS; ++r) {
    int slot = r * 256 + tid;
    int row = slot >> 2, sp = slot & 3;
    int seg = sp ^ ((row >> 1) & 3);
    aofs[r] = (size_t)row * CI + seg * 8;
  }
  size_t bofs[BROUNDS];
  bool bcolv[BROUNDS];
#pragma unroll
  for (int r = 0; r < BROUNDS; ++r) {
    int slot = r * 256 + tid;
    int pxl = slot >> 2, sp = slot & 3;
    int seg = sp ^ ((pxl >> 1) & 3);
    int px = pxl - HALO;
    bcolv[r] = ((unsigned)px < 256u) && (pxl < BPXMAX);
    bofs[r] = (size_t)px * CI + seg * 8;
  }

  f32x4 acc[MF][8];
  const f32x4 zf = {0.f, 0.f, 0.f, 0.f};
#pragma unroll
  for (int m = 0; m < MF; ++m)
#pragma unroll
    for (int n = 0; n < 8; ++n) acc[m][n] = zf;

  int dy = 0, c = 0;
#pragma unroll 1
  for (int ph = 0; ph < NPH; ++ph) {
    __syncthreads();                 // protect LDS from prev phase readers
    const u16* Wph = Wp + ((size_t)dy * APLN) * CI + c * 32;
#pragma unroll
    for (int r = 0; r < AROUNDS; ++r)
      gload16(Wph + aofs[r], &lds[r * 2048 + wv * 512]);
    const int hin = (KS == 3) ? (h + dy - 1) : h;
    const bool rv = (unsigned)hin < 256u;
    const u16* Brow = Xin + ((size_t)((bi << 8) + (rv ? hin : 0)) << 8) * CI + c * 32;
#pragma unroll
    for (int r = 0; r < BROUNDS; ++r) {
      const u16* src = (rv && bcolv[r]) ? (Brow + bofs[r]) : zbuf;
      gload16(src, &lds[AELEMS + r * 2048 + wv * 512]);
    }
    __syncthreads();                 // staging complete

#pragma unroll
    for (int dx = 0; dx < NDX; ++dx) {
      short8 bfr[8];
#pragma unroll
      for (int n = 0; n < 8; ++n) {
        int p = wn * 128 + n * 16 + l15;
        int pxl = (KS == 3) ? (p + dx + 1) : p;   // px = p+dx-1, slot = px+HALO
        int ba = (AELEMS * 2) + pxl * 64 + ((segr ^ ((pxl >> 1) & 3)) << 4);
        bfr[n] = *(const short8*)((const char*)lds + ba);
      }
      short8 afr[MF];
#pragma unroll
      for (int m = 0; m < MF; ++m) {
        int row = dx * BM + wm * (BM / 2) + m * 16 + l15;
        int aa = row * 64 + ((segr ^ ((row >> 1) & 3)) << 4);
        afr[m] = *(const short8*)((const char*)lds + aa);
      }
#pragma unroll
      for (int m = 0; m < MF; ++m)
#pragma unroll
        for (int n = 0; n < 8; ++n) mfma16(afr[m], bfr[n], acc[m][n]);
    }
    if (++c == NCH) { c = 0; ++dy; }
  }
  asm volatile("s_nop 7\n\ts_nop 7");   // MFMA -> VALU hazard insurance

  const int co_sub = (lane >> 4) << 2;
  const size_t pixbase = ((size_t)((bi << 8) + h)) << 8;
#pragma unroll
  for (int m = 0; m < MF; ++m) {
    const int co = wm * (BM / 2) + m * 16 + co_sub;
#pragma unroll
    for (int n = 0; n < 8; ++n) {
      const int px = wn * 128 + n * 16 + l15;
      f32x4 v = acc[m][n];
      float t[4];
#pragma unroll
      for (int r = 0; r < 4; ++r) {
        float x = v[r] + bias[co + r];
        if (LRELU) x = x > 0.f ? x : 0.1f * x;
        t[r] = x;
      }
      if (OBF) {
        ushort4 u;
        u.x = rne_bf16(t[0]); u.y = rne_bf16(t[1]);
        u.z = rne_bf16(t[2]); u.w = rne_bf16(t[3]);
        *(ushort4*)(Xout + (pixbase + px) * OSTRIDE + co) = u;
      }
      if (COF32 > 0) {
#pragma unroll
        for (int r = 0; r < 4; ++r) {
          int cch = co + r;
          if (cch < COF32)
            outF[(((size_t)bi * COF32 + cch) << 16) + (h << 8) + px] = t[r];
        }
      }
    }
  }
}

// ---------------------------------------------------------------------------
extern "C" void kernel_launch(void* const* d_in, const int* in_sizes, int n_in,
                              void* d_out, int out_size, void* d_ws, size_t ws_size,
                              hipStream_t stream) {
  const float* feat0 = (const float*)d_in[0];
  const float* feat1 = (const float*)d_in[1];
  const float* lfeat = (const float*)d_in[2];
  const float* lflow = (const float*)d_in[3];
  const float* w1 = (const float*)d_in[4];  const float* b1 = (const float*)d_in[5];
  const float* w2 = (const float*)d_in[6];  const float* b2 = (const float*)d_in[7];
  const float* w3 = (const float*)d_in[8];  const float* b3 = (const float*)d_in[9];
  const float* w4 = (const float*)d_in[10]; const float* b4 = (const float*)d_in[11];
  const float* w5 = (const float*)d_in[12]; const float* b5 = (const float*)d_in[13];
  const float* w6 = (const float*)d_in[14]; const float* b6 = (const float*)d_in[15];

  u16* ws = (u16*)d_ws;
  u16* X1 = ws;
  u16* X2 = ws + 33554432;
  u16* X3 = ws;
  u16* X4 = ws + 33554432;
  u16* X5 = ws;
  u16* X6 = ws + 33554432;
  u16* f0q = ws + 33554432;      // [2][12][65536][4] f16 (consumed before X2 written)
  u16* f1q = ws + 39845888;
  u16* w1p = ws + 54525952;      // [192][256]
  u16* w2p = w1p + 49152;        // [3][384][160]
  u16* w3p = w2p + 184320;       // [3][384][128]
  u16* w4p = w3p + 147456;       // [3][320][128]
  u16* w5p = w4p + 147456;       // [3][192][96]
  u16* w6p = w5p + 55296;        // [3][128][64] (convr layout, co/rows padded)
  float* bp = (float*)(w6p + 24576);  // 608 f32: b1|b2|b3p|b4|b5|b6p
  u16* zbuf = (u16*)(bp + 608);       // 128 zero bf16 (256B zeros)

  const float* bp1 = bp;
  const float* bp2 = bp + 160;
  const float* bp3 = bp + 288;
  const float* bp4 = bp + 416;
  const float* bp5 = bp + 512;
  const float* bp6 = bp + 576;

  float* flow = (float*)d_out;              // [2][4][256][256]
  float* xout = (float*)d_out + 524288;     // [2][64][256][256]

  prep1_kernel<<<192, 256, 0, stream>>>(w1, w1p);
  prep3s_kernel<128, 160, 128, 384, 160><<<720, 256, 0, stream>>>(w2, w2p);
  prep3s_kernel<112, 128, 128, 384, 128><<<576, 256, 0, stream>>>(w3, w3p);
  prep3s_kernel< 96, 112,  96, 320, 128><<<480, 256, 0, stream>>>(w4, w4p);
  prep3s_kernel< 64,  96,  64, 192,  96><<<216, 256, 0, stream>>>(w5, w5p);
  prep3s_kernel<  4,  64,  32, 128,  64><<< 96, 256, 0, stream>>>(w6, w6p);
  prep_bias_kernel<<<3, 256, 0, stream>>>(b1, b2, b3, b4, b5, b6, bp, zbuf);

  quadize_kernel<<<1024, 256, 0, stream>>>(feat0, feat1, f0q, f1q);
  concat68_kernel<<<2048, 256, 0, stream>>>(lfeat, lflow, X1);
  corr5_kernel<<<1024, 256, 0, stream>>>(f0q, f1q, zbuf, X1);

  // <CI, BM, APLN, KS, OSTRIDE, LRELU, OBF, COF32>  -- full-row, grid 512
  convr_kernel<256, 160, 192, 1, 160, true,  true,  0><<<512, 256, 0, stream>>>(X1, w1p, bp1, zbuf, X2, nullptr);
  convr_kernel<160, 128, 384, 3, 128, true,  true,  0><<<512, 256, 0, stream>>>(X2, w2p, bp2, zbuf, X3, nullptr);
  convr_kernel<128, 128, 384, 3, 128, true,  true,  0><<<512, 256, 0, stream>>>(X3, w3p, bp3, zbuf, X4, nullptr);
  convr_kernel<128,  96, 320, 3,  96, true,  true,  0><<<512, 256, 0, stream>>>(X4, w4p, bp4, zbuf, X5, nullptr);
  convr_kernel< 96,  64, 192, 3,  64, true,  true, 64><<<512, 256, 0, stream>>>(X5, w5p, bp5, zbuf, X6, xout);
  convr_kernel< 64,  32, 128, 3,   1, false, false, 4><<<512, 256, 0, stream>>>(X6, w6p, bp6, zbuf, nullptr, flow);
}